// Round 1
// baseline (1139.271 us; speedup 1.0000x reference)
//
#include <hip/hip_runtime.h>
#include <hip/hip_bf16.h>

#define BB 4
#define CC 256
#define CI 128
#define NPIX 9216      // 96*96
#define MPIX 2304      // 48*48
#define WIMG 96
#define WPOOL 48

// ---------------- K1: theta/g/phi 1x1 convs as GEMM: tpg[b][o][p], o<384 ----
__global__ __launch_bounds__(256) void k_conv3(
    const float* __restrict__ x,
    const float* __restrict__ Wt, const float* __restrict__ bt,
    const float* __restrict__ Wg, const float* __restrict__ bg,
    const float* __restrict__ Wp, const float* __restrict__ bp,
    float* __restrict__ tpg)
{
  const int pt = blockIdx.x, ot = blockIdx.y, b = blockIdx.z;
  const int p0 = pt * 64, o0 = ot * 64;
  const float* Wsel; const float* bsel;
  if (o0 < 128)      { Wsel = Wt;            bsel = bt;        }
  else if (o0 < 256) { Wsel = Wg - 128 * CC; bsel = bg - 128;  }
  else               { Wsel = Wp - 256 * CC; bsel = bp - 256;  }
  __shared__ float Wl[64][33];
  __shared__ float Xl[32][68];
  const int t = threadIdx.x;
  const int to = t >> 4, tp = t & 15;
  float acc[4][4] = {{0.f}};
  for (int kk = 0; kk < CC; kk += 32) {
    #pragma unroll
    for (int i = 0; i < 8; ++i) {
      int idx = i * 256 + t, r = idx >> 5, c = idx & 31;
      Wl[r][c] = Wsel[(o0 + r) * CC + kk + c];
    }
    #pragma unroll
    for (int i = 0; i < 8; ++i) {
      int idx = i * 256 + t, r = idx >> 6, c = idx & 63;
      Xl[r][c] = x[(b * CC + kk + r) * NPIX + p0 + c];
    }
    __syncthreads();
    #pragma unroll 8
    for (int k = 0; k < 32; ++k) {
      float a[4];
      #pragma unroll
      for (int i = 0; i < 4; ++i) a[i] = Wl[to * 4 + i][k];
      float4 bv = *(const float4*)&Xl[k][tp * 4];
      float bb[4] = {bv.x, bv.y, bv.z, bv.w};
      #pragma unroll
      for (int i = 0; i < 4; ++i)
        #pragma unroll
        for (int j = 0; j < 4; ++j)
          acc[i][j] += a[i] * bb[j];
    }
    __syncthreads();
  }
  #pragma unroll
  for (int i = 0; i < 4; ++i) {
    int o = o0 + to * 4 + i;
    float bias = bsel[o];
    float4 v = make_float4(acc[i][0] + bias, acc[i][1] + bias,
                           acc[i][2] + bias, acc[i][3] + bias);
    *(float4*)&tpg[(b * 384 + o) * NPIX + p0 + tp * 4] = v;
  }
}

// ---------------- K2: 2x2 maxpool of g/phi ---------------------------------
__global__ __launch_bounds__(256) void k_pool(
    const float* __restrict__ tpg,
    float* __restrict__ gbuf, float* __restrict__ phibuf)
{
  int idx = blockIdx.x * 256 + threadIdx.x;
  const int total = BB * 2 * CI * MPIX;
  if (idx >= total) return;
  int mp = idx % MPIX;
  int r  = idx / MPIX;
  int c2 = r % (2 * CI);
  int b  = r / (2 * CI);
  int hp = mp / WPOOL, wp = mp % WPOOL;
  const float* src = &tpg[(b * 384 + 128 + c2) * NPIX + (2 * hp) * WIMG + 2 * wp];
  float v = fmaxf(fmaxf(src[0], src[1]), fmaxf(src[WIMG], src[WIMG + 1]));
  if (c2 < CI) gbuf[(b * CI + c2) * MPIX + mp] = v;
  else         phibuf[(b * CI + (c2 - CI)) * MPIX + mp] = v;
}

// ---------------- K3: flash attention, fp32 --------------------------------
// Q tile = 64 queries, K/V tile = 64. Th: [128][64]; PG: phi(stride 64)/g(stride 65);
// P stored bf16 in Sl (stride 66). Online softmax in registers (shfl width 16).
__global__ __launch_bounds__(256) void k_attn(
    const float* __restrict__ tpg,
    const float* __restrict__ gbuf, const float* __restrict__ phibuf,
    float* __restrict__ ybuf)
{
  const int qt = blockIdx.x, b = blockIdx.y;
  const int n0 = qt * 64;
  __shared__ float Th[CI][64];               // 32 KB
  __shared__ float PG[CI * 65];              // 33.3 KB
  __shared__ unsigned short Sl[64 * 66];     // 8.4 KB (P in bf16)
  __shared__ float mrun[64], lrun[64], scal[64];
  const int t = threadIdx.x;
  const int tq = t >> 4, tm = t & 15;        // scores mapping: q=4tq+i, m=4tm+j
  const int tc = tq, tq2 = tm;               // PV mapping: c=8tc+i, q=4tq2+j

  #pragma unroll
  for (int i = 0; i < 8; ++i) {
    int idx = i * 256 + t, c = idx >> 4, q4 = (idx & 15) << 2;
    *(float4*)&Th[c][q4] = *(const float4*)&tpg[(b * 384 + c) * NPIX + n0 + q4];
  }
  if (t < 64) { mrun[t] = -1e30f; lrun[t] = 0.f; }
  float yacc[8][4] = {{0.f}};
  __syncthreads();

  for (int m0 = 0; m0 < MPIX; m0 += 64) {
    // load phi tile (stride 64)
    #pragma unroll
    for (int i = 0; i < 8; ++i) {
      int idx = i * 256 + t, c = idx >> 4, m4 = (idx & 15) << 2;
      *(float4*)&PG[c * 64 + m4] =
          *(const float4*)&phibuf[(b * CI + c) * MPIX + m0 + m4];
    }
    __syncthreads();

    // scores: s[i][j] = sum_c Th[c][4tq+i] * PG[c][4tm+j]
    float s[4][4] = {{0.f}};
    #pragma unroll 4
    for (int c = 0; c < CI; ++c) {
      float4 av = *(const float4*)&Th[c][tq * 4];
      float4 bv = *(const float4*)&PG[c * 64 + tm * 4];
      float aa[4] = {av.x, av.y, av.z, av.w};
      float bb[4] = {bv.x, bv.y, bv.z, bv.w};
      #pragma unroll
      for (int i = 0; i < 4; ++i)
        #pragma unroll
        for (int j = 0; j < 4; ++j)
          s[i][j] += aa[i] * bb[j];
    }

    // online softmax per row (16 lanes per row, shfl width 16)
    #pragma unroll
    for (int i = 0; i < 4; ++i) {
      float mx = fmaxf(fmaxf(s[i][0], s[i][1]), fmaxf(s[i][2], s[i][3]));
      mx = fmaxf(mx, __shfl_xor(mx, 1, 16));
      mx = fmaxf(mx, __shfl_xor(mx, 2, 16));
      mx = fmaxf(mx, __shfl_xor(mx, 4, 16));
      mx = fmaxf(mx, __shfl_xor(mx, 8, 16));
      float mo = mrun[4 * tq + i];
      float mn = fmaxf(mo, mx);
      float sum = 0.f;
      #pragma unroll
      for (int j = 0; j < 4; ++j) {
        float pv = __expf(s[i][j] - mn);
        s[i][j] = pv;
        sum += pv;
      }
      sum += __shfl_xor(sum, 1, 16);
      sum += __shfl_xor(sum, 2, 16);
      sum += __shfl_xor(sum, 4, 16);
      sum += __shfl_xor(sum, 8, 16);
      if (tm == 0) {
        float sc = __expf(mo - mn);
        scal[4 * tq + i] = sc;
        lrun[4 * tq + i] = lrun[4 * tq + i] * sc + sum;
        mrun[4 * tq + i] = mn;
      }
      #pragma unroll
      for (int j = 0; j < 4; ++j) {
        unsigned int u = __float_as_uint(s[i][j]);
        Sl[(4 * tq + i) * 66 + 4 * tm + j] = (unsigned short)((u + 0x8000u) >> 16);
      }
    }
    __syncthreads();   // scores done reading PG(phi); Sl/scal visible

    // load g tile (stride 65)
    #pragma unroll
    for (int i = 0; i < 8; ++i) {
      int idx = i * 256 + t, c = idx >> 4, m4 = (idx & 15) << 2;
      float4 gv = *(const float4*)&gbuf[(b * CI + c) * MPIX + m0 + m4];
      PG[c * 65 + m4 + 0] = gv.x;
      PG[c * 65 + m4 + 1] = gv.y;
      PG[c * 65 + m4 + 2] = gv.z;
      PG[c * 65 + m4 + 3] = gv.w;
    }
    __syncthreads();

    // PV: yacc[c][q] = yacc*scal[q] + sum_m P[q][m]*g[c][m]
    float sc[4];
    #pragma unroll
    for (int j = 0; j < 4; ++j) sc[j] = scal[4 * tq2 + j];
    #pragma unroll
    for (int i = 0; i < 8; ++i)
      #pragma unroll
      for (int j = 0; j < 4; ++j)
        yacc[i][j] *= sc[j];
    #pragma unroll 2
    for (int m = 0; m < 64; ++m) {
      float pv[4], gv[8];
      #pragma unroll
      for (int j = 0; j < 4; ++j) {
        unsigned int u = (unsigned int)Sl[(4 * tq2 + j) * 66 + m];
        pv[j] = __uint_as_float(u << 16);
      }
      #pragma unroll
      for (int i = 0; i < 8; ++i) gv[i] = PG[(8 * tc + i) * 65 + m];
      #pragma unroll
      for (int i = 0; i < 8; ++i)
        #pragma unroll
        for (int j = 0; j < 4; ++j)
          yacc[i][j] += gv[i] * pv[j];
    }
    __syncthreads();   // before next tile overwrites PG/Sl
  }

  float inv[4];
  #pragma unroll
  for (int j = 0; j < 4; ++j) inv[j] = 1.0f / lrun[4 * tq2 + j];
  #pragma unroll
  for (int i = 0; i < 8; ++i)
    #pragma unroll
    for (int j = 0; j < 4; ++j)
      ybuf[(b * CI + 8 * tc + i) * NPIX + n0 + 4 * tq2 + j] = yacc[i][j] * inv[j];
}

// ---------------- K4: W-conv GEMM: z[b][o][n] -> tpg[b][128+o][n] ----------
__global__ __launch_bounds__(256) void k_wconv(
    const float* __restrict__ ybuf,
    const float* __restrict__ Ww, const float* __restrict__ bw,
    float* __restrict__ tpg)
{
  const int pt = blockIdx.x, ot = blockIdx.y, b = blockIdx.z;
  const int p0 = pt * 64, o0 = ot * 64;
  __shared__ float Wl[64][33];
  __shared__ float Xl[32][68];
  const int t = threadIdx.x;
  const int to = t >> 4, tp = t & 15;
  float acc[4][4] = {{0.f}};
  for (int kk = 0; kk < CI; kk += 32) {
    #pragma unroll
    for (int i = 0; i < 8; ++i) {
      int idx = i * 256 + t, r = idx >> 5, c = idx & 31;
      Wl[r][c] = Ww[(o0 + r) * CI + kk + c];
    }
    #pragma unroll
    for (int i = 0; i < 8; ++i) {
      int idx = i * 256 + t, r = idx >> 6, c = idx & 63;
      Xl[r][c] = ybuf[(b * CI + kk + r) * NPIX + p0 + c];
    }
    __syncthreads();
    #pragma unroll 8
    for (int k = 0; k < 32; ++k) {
      float a[4];
      #pragma unroll
      for (int i = 0; i < 4; ++i) a[i] = Wl[to * 4 + i][k];
      float4 bv = *(const float4*)&Xl[k][tp * 4];
      float bb[4] = {bv.x, bv.y, bv.z, bv.w};
      #pragma unroll
      for (int i = 0; i < 4; ++i)
        #pragma unroll
        for (int j = 0; j < 4; ++j)
          acc[i][j] += a[i] * bb[j];
    }
    __syncthreads();
  }
  #pragma unroll
  for (int i = 0; i < 4; ++i) {
    int o = o0 + to * 4 + i;
    float bias = bw[o];
    float4 v = make_float4(acc[i][0] + bias, acc[i][1] + bias,
                           acc[i][2] + bias, acc[i][3] + bias);
    *(float4*)&tpg[(b * 384 + 128 + o) * NPIX + p0 + tp * 4] = v;
  }
}

// ---------------- K4b: per-channel batch stats -----------------------------
__global__ __launch_bounds__(256) void k_stats(
    const float* __restrict__ tpg, float* __restrict__ stats)
{
  const int o = blockIdx.x, t = threadIdx.x;
  float s = 0.f, s2 = 0.f;
  for (int b = 0; b < BB; ++b) {
    const float* z = &tpg[(b * 384 + 128 + o) * NPIX];
    for (int i = t; i < NPIX / 4; i += 256) {
      float4 v = *(const float4*)&z[i * 4];
      s  += v.x + v.y + v.z + v.w;
      s2 += v.x * v.x + v.y * v.y + v.z * v.z + v.w * v.w;
    }
  }
  #pragma unroll
  for (int off = 1; off < 64; off <<= 1) {
    s  += __shfl_xor(s,  off, 64);
    s2 += __shfl_xor(s2, off, 64);
  }
  __shared__ float ls[4], ls2[4];
  if ((t & 63) == 0) { ls[t >> 6] = s; ls2[t >> 6] = s2; }
  __syncthreads();
  if (t == 0) {
    float S  = ls[0] + ls[1] + ls[2] + ls[3];
    float S2 = ls2[0] + ls2[1] + ls2[2] + ls2[3];
    const float invn = 1.0f / (float)(BB * NPIX);
    float mean = S * invn;
    float var  = S2 * invn - mean * mean;
    stats[o] = mean;
    stats[CC + o] = rsqrtf(var + 1e-5f);
  }
}

// ---------------- K5: BN apply + residual ----------------------------------
__global__ __launch_bounds__(256) void k_out(
    const float* __restrict__ tpg, const float* __restrict__ x,
    const float* __restrict__ gamma, const float* __restrict__ beta,
    const float* __restrict__ stats, float* __restrict__ out)
{
  int idx = blockIdx.x * 256 + threadIdx.x;
  const int total4 = BB * CC * NPIX / 4;
  if (idx >= total4) return;
  int e = idx * 4;
  int p = e % NPIX;
  int o = (e / NPIX) % CC;
  int b = e / (CC * NPIX);
  float a  = stats[CC + o] * gamma[o];
  float c0 = beta[o] - stats[o] * a;
  float4 z  = *(const float4*)&tpg[(b * 384 + 128 + o) * NPIX + p];
  float4 xv = *(const float4*)&x[e];
  float4 rv;
  rv.x = z.x * a + c0 + xv.x;
  rv.y = z.y * a + c0 + xv.y;
  rv.z = z.z * a + c0 + xv.z;
  rv.w = z.w * a + c0 + xv.w;
  *(float4*)&out[e] = rv;
}

extern "C" void kernel_launch(void* const* d_in, const int* in_sizes, int n_in,
                              void* d_out, int out_size, void* d_ws, size_t ws_size,
                              hipStream_t stream)
{
  const float* x     = (const float*)d_in[0];
  const float* Wg    = (const float*)d_in[1];
  const float* bg    = (const float*)d_in[2];
  const float* Wt    = (const float*)d_in[3];
  const float* bt    = (const float*)d_in[4];
  const float* Wp    = (const float*)d_in[5];
  const float* bp    = (const float*)d_in[6];
  const float* Ww    = (const float*)d_in[7];
  const float* bw    = (const float*)d_in[8];
  const float* gamma = (const float*)d_in[9];
  const float* beta  = (const float*)d_in[10];
  float* out = (float*)d_out;

  float* ws     = (float*)d_ws;
  float* tpg    = ws;                                  // [BB][384][NPIX]
  float* gbuf   = tpg + (size_t)BB * 384 * NPIX;       // [BB][CI][MPIX]
  float* phibuf = gbuf + (size_t)BB * CI * MPIX;       // [BB][CI][MPIX]
  float* ybuf   = phibuf + (size_t)BB * CI * MPIX;     // [BB][CI][NPIX]
  float* stats  = ybuf + (size_t)BB * CI * NPIX;       // [2][CC]

  dim3 g1(NPIX / 64, 384 / 64, BB);
  k_conv3<<<g1, 256, 0, stream>>>(x, Wt, bt, Wg, bg, Wp, bp, tpg);

  k_pool<<<(BB * 2 * CI * MPIX + 255) / 256, 256, 0, stream>>>(tpg, gbuf, phibuf);

  dim3 g3(NPIX / 64, BB);
  k_attn<<<g3, 256, 0, stream>>>(tpg, gbuf, phibuf, ybuf);

  dim3 g4(NPIX / 64, CC / 64, BB);
  k_wconv<<<g4, 256, 0, stream>>>(ybuf, Ww, bw, tpg);

  k_stats<<<CC, 256, 0, stream>>>(tpg, stats);

  k_out<<<(BB * CC * NPIX / 4 + 255) / 256, 256, 0, stream>>>(tpg, x, gamma, beta, stats, out);
}

// Round 4
// 398.373 us; speedup vs baseline: 2.8598x; 2.8598x over previous
//
#include <hip/hip_runtime.h>
#include <hip/hip_bf16.h>

#define BB 4
#define CC 256
#define CI 128
#define NPIX 9216      // 96*96
#define MPIX 2304      // 48*48
#define WIMG 96
#define WPOOL 48

typedef _Float16 f16x2 __attribute__((ext_vector_type(2)));
typedef _Float16 f16x4 __attribute__((ext_vector_type(4)));
typedef _Float16 f16x8 __attribute__((ext_vector_type(8)));
typedef float f32x4 __attribute__((ext_vector_type(4)));

// ---------------- K1: theta/g/phi 1x1 convs as GEMM: tpg[b][o][p], o<384 ----
__global__ __launch_bounds__(256) void k_conv3(
    const float* __restrict__ x,
    const float* __restrict__ Wt, const float* __restrict__ bt,
    const float* __restrict__ Wg, const float* __restrict__ bg,
    const float* __restrict__ Wp, const float* __restrict__ bp,
    float* __restrict__ tpg)
{
  const int pt = blockIdx.x, ot = blockIdx.y, b = blockIdx.z;
  const int p0 = pt * 64, o0 = ot * 64;
  const float* Wsel; const float* bsel;
  if (o0 < 128)      { Wsel = Wt;            bsel = bt;        }
  else if (o0 < 256) { Wsel = Wg - 128 * CC; bsel = bg - 128;  }
  else               { Wsel = Wp - 256 * CC; bsel = bp - 256;  }
  __shared__ float Wl[64][33];
  __shared__ float Xl[32][68];
  const int t = threadIdx.x;
  const int to = t >> 4, tp = t & 15;
  float acc[4][4] = {{0.f}};
  for (int kk = 0; kk < CC; kk += 32) {
    #pragma unroll
    for (int i = 0; i < 8; ++i) {
      int idx = i * 256 + t, r = idx >> 5, c = idx & 31;
      Wl[r][c] = Wsel[(o0 + r) * CC + kk + c];
    }
    #pragma unroll
    for (int i = 0; i < 8; ++i) {
      int idx = i * 256 + t, r = idx >> 6, c = idx & 63;
      Xl[r][c] = x[(size_t)(b * CC + kk + r) * NPIX + p0 + c];
    }
    __syncthreads();
    #pragma unroll 8
    for (int k = 0; k < 32; ++k) {
      float a[4];
      #pragma unroll
      for (int i = 0; i < 4; ++i) a[i] = Wl[to * 4 + i][k];
      float4 bv = *(const float4*)&Xl[k][tp * 4];
      float bb[4] = {bv.x, bv.y, bv.z, bv.w};
      #pragma unroll
      for (int i = 0; i < 4; ++i)
        #pragma unroll
        for (int j = 0; j < 4; ++j)
          acc[i][j] += a[i] * bb[j];
    }
    __syncthreads();
  }
  #pragma unroll
  for (int i = 0; i < 4; ++i) {
    int o = o0 + to * 4 + i;
    float bias = bsel[o];
    float4 v = make_float4(acc[i][0] + bias, acc[i][1] + bias,
                           acc[i][2] + bias, acc[i][3] + bias);
    *(float4*)&tpg[(size_t)(b * 384 + o) * NPIX + p0 + tp * 4] = v;
  }
}

// ---------------- K2a: theta transpose + fp16: th_h[b][n][c] ---------------
__global__ __launch_bounds__(256) void k_mkq(
    const float* __restrict__ tpg, _Float16* __restrict__ th_h)
{
  const int nt = blockIdx.x, ct = blockIdx.y, b = blockIdx.z;
  const int n0 = nt * 64, c0 = ct * 64;
  __shared__ float L[64][65];
  const int t = threadIdx.x;
  #pragma unroll
  for (int i = 0; i < 16; ++i) {
    int idx = i * 256 + t, c = idx >> 6, n = idx & 63;
    L[c][n] = tpg[(size_t)(b * 384 + c0 + c) * NPIX + n0 + n];
  }
  __syncthreads();
  #pragma unroll
  for (int i = 0; i < 4; ++i) {
    int idx = i * 256 + t, n = idx >> 4, cg = idx & 15;
    f16x4 v;
    v[0] = (_Float16)L[cg * 4 + 0][n]; v[1] = (_Float16)L[cg * 4 + 1][n];
    v[2] = (_Float16)L[cg * 4 + 2][n]; v[3] = (_Float16)L[cg * 4 + 3][n];
    *(f16x4*)&th_h[(size_t)(b * NPIX + n0 + n) * 128 + c0 + cg * 4] = v;
  }
}

// ---------------- K2b: 2x2 maxpool -> fp16: phi[b][m][c], g[b][c][m] -------
__global__ __launch_bounds__(256) void k_pool2(
    const float* __restrict__ tpg,
    _Float16* __restrict__ g_h, _Float16* __restrict__ phi_h)
{
  const int mt = blockIdx.x, ct = blockIdx.y, b = blockIdx.z;
  const int m0 = mt * 64, c0 = ct * 32;
  __shared__ float Lg[32][66], Lp[32][66];
  const int t = threadIdx.x;
  #pragma unroll
  for (int i = 0; i < 8; ++i) {
    int idx = i * 256 + t, c = idx >> 6, m = idx & 63;
    int mm = m0 + m, hp = mm / WPOOL, wp = mm % WPOOL;
    const float* sg = &tpg[(size_t)(b * 384 + 128 + c0 + c) * NPIX + hp * 2 * WIMG + wp * 2];
    Lg[c][m] = fmaxf(fmaxf(sg[0], sg[1]), fmaxf(sg[WIMG], sg[WIMG + 1]));
    const float* sp = sg + (size_t)128 * NPIX;
    Lp[c][m] = fmaxf(fmaxf(sp[0], sp[1]), fmaxf(sp[WIMG], sp[WIMG + 1]));
  }
  __syncthreads();
  {
    int c = t >> 3, mq = t & 7;
    f16x4 v0, v1;
    v0[0] = (_Float16)Lg[c][mq * 8 + 0]; v0[1] = (_Float16)Lg[c][mq * 8 + 1];
    v0[2] = (_Float16)Lg[c][mq * 8 + 2]; v0[3] = (_Float16)Lg[c][mq * 8 + 3];
    v1[0] = (_Float16)Lg[c][mq * 8 + 4]; v1[1] = (_Float16)Lg[c][mq * 8 + 5];
    v1[2] = (_Float16)Lg[c][mq * 8 + 6]; v1[3] = (_Float16)Lg[c][mq * 8 + 7];
    _Float16* dst = &g_h[(size_t)(b * CI + c0 + c) * MPIX + m0 + mq * 8];
    *(f16x4*)dst = v0;
    *(f16x4*)(dst + 4) = v1;
  }
  #pragma unroll
  for (int i = 0; i < 2; ++i) {
    int idx = i * 256 + t, m = idx >> 3, cg = idx & 7;
    f16x4 v;
    v[0] = (_Float16)Lp[cg * 4 + 0][m]; v[1] = (_Float16)Lp[cg * 4 + 1][m];
    v[2] = (_Float16)Lp[cg * 4 + 2][m]; v[3] = (_Float16)Lp[cg * 4 + 3][m];
    *(f16x4*)&phi_h[(size_t)(b * MPIX + m0 + m) * 128 + c0 + cg * 4] = v;
  }
}

// ---------------- K3: flash attention, fp16 MFMA ----------------------------
// Q-tile 128 (4 waves x 32 q). K-tile 64. Swapped QK^T: S^T = mfma(phi, theta)
// so softmax rows are lane-local. P (fp16) -> wave-private swizzled LDS.
__global__ __launch_bounds__(256, 2) void k_attn(
    const _Float16* __restrict__ th_h,
    const _Float16* __restrict__ phi_h,
    const _Float16* __restrict__ g_h,
    float* __restrict__ ybuf)
{
  const int qt = blockIdx.x, b = blockIdx.y;
  const int n0 = qt * 128;
  __shared__ _Float16 Ph[64 * 128];     // [m][c] swizzled, 16 KB
  __shared__ _Float16 Gl[128 * 64];     // [c][m] swizzled, 16 KB
  __shared__ _Float16 Pl[4 * 32 * 64];  // per-wave P, swizzled, 16 KB
  char* PhB = (char*)Ph;
  char* GlB = (char*)Gl;
  char* PlB = (char*)Pl;

  const int tid = threadIdx.x;
  const int l = tid & 63, wid = tid >> 6;
  const int l15 = l & 15, g16 = l >> 4;
  const int wq0 = wid * 32;

  // theta fragments (block-constant) straight from global into regs
  f16x8 thf[2][4];
  #pragma unroll
  for (int qh = 0; qh < 2; ++qh) {
    const size_t row = (size_t)(b * NPIX + n0 + wq0 + 16 * qh + l15) * 128;
    #pragma unroll
    for (int cs = 0; cs < 4; ++cs)
      thf[qh][cs] = *(const f16x8*)&th_h[row + 32 * cs + 8 * g16];
  }

  // stage tile 0
  #pragma unroll
  for (int i = 0; i < 4; ++i) {
    int idx = i * 256 + tid, m = idx >> 4, cg = idx & 15;
    int4 v = *(const int4*)&phi_h[((size_t)(b * MPIX + m) << 7) + cg * 8];
    *(int4*)(PhB + m * 256 + ((cg * 16) ^ ((m & 7) << 4))) = v;
  }
  #pragma unroll
  for (int i = 0; i < 4; ++i) {
    int idx = i * 256 + tid, c = idx >> 3, cg = idx & 7;
    int4 v = *(const int4*)&g_h[(size_t)(b * CI + c) * MPIX + cg * 8];
    *(int4*)(GlB + c * 128 + ((cg * 16) ^ ((c & 7) << 4))) = v;
  }
  __syncthreads();

  f32x4 yacc[2][8] = {};
  float mrun[2] = {-1e30f, -1e30f};
  float lrun[2] = {0.f, 0.f};

  for (int kt = 0; kt < 36; ++kt) {
    int4 stA[4], stB[4];
    const bool pf = (kt + 1 < 36);
    if (pf) {
      const int m1 = (kt + 1) * 64;
      #pragma unroll
      for (int i = 0; i < 4; ++i) {
        int idx = i * 256 + tid, m = idx >> 4, cg = idx & 15;
        stA[i] = *(const int4*)&phi_h[((size_t)(b * MPIX + m1 + m) << 7) + cg * 8];
      }
      #pragma unroll
      for (int i = 0; i < 4; ++i) {
        int idx = i * 256 + tid, c = idx >> 3, cg = idx & 7;
        stB[i] = *(const int4*)&g_h[(size_t)(b * CI + c) * MPIX + m1 + cg * 8];
      }
    }

    // ---- scores: S^T[m][q] ----
    f32x4 sacc[4][2] = {};
    #pragma unroll
    for (int cs = 0; cs < 4; ++cs) {
      const int cb = cs * 64 + g16 * 16;
      #pragma unroll
      for (int mf = 0; mf < 4; ++mf) {
        const int m = 16 * mf + l15;
        f16x8 aph = *(const f16x8*)(PhB + m * 256 + (cb ^ ((m & 7) << 4)));
        sacc[mf][0] = __builtin_amdgcn_mfma_f32_16x16x32_f16(aph, thf[0][cs], sacc[mf][0], 0, 0, 0);
        sacc[mf][1] = __builtin_amdgcn_mfma_f32_16x16x32_f16(aph, thf[1][cs], sacc[mf][1], 0, 0, 0);
      }
    }

    // ---- online softmax (lane owns q = wq0 + 16*qh + l15) ----
    // P rounded to fp16; lrun summed over the ROUNDED values so the
    // numerator (PV) and denominator stay consistent.
    float scl2[2];
    f16x4 pr[4][2];
    #pragma unroll
    for (int qh = 0; qh < 2; ++qh) {
      float mx = -1e30f;
      #pragma unroll
      for (int mf = 0; mf < 4; ++mf)
        #pragma unroll
        for (int r = 0; r < 4; ++r) mx = fmaxf(mx, sacc[mf][qh][r]);
      mx = fmaxf(mx, __shfl_xor(mx, 16, 64));
      mx = fmaxf(mx, __shfl_xor(mx, 32, 64));
      const float mo = mrun[qh];
      const float mn = fmaxf(mo, mx);
      float sum = 0.f;
      #pragma unroll
      for (int mf = 0; mf < 4; ++mf)
        #pragma unroll
        for (int r = 0; r < 4; ++r) {
          float p = __expf(sacc[mf][qh][r] - mn);
          _Float16 ph = (_Float16)p;
          pr[mf][qh][r] = ph;
          sum += (float)ph;
        }
      sum += __shfl_xor(sum, 16, 64);
      sum += __shfl_xor(sum, 32, 64);
      const float sc = __expf(mo - mn);
      scl2[qh] = sc;
      lrun[qh] = lrun[qh] * sc + sum;
      mrun[qh] = mn;
    }

    // ---- P -> wave-private LDS (fp16, swizzled) ----
    #pragma unroll
    for (int qh = 0; qh < 2; ++qh) {
      const int qw = l15 + 16 * qh;
      char* prow = PlB + (wid << 12) + qw * 128;
      #pragma unroll
      for (int mf = 0; mf < 4; ++mf)
        *(f16x4*)(prow + ((32 * mf + 8 * g16) ^ ((qw & 7) << 4))) = pr[mf][qh];
    }

    // ---- rescale yacc by exp(m_old - m_new) ----
    {
      float rs[2][4];
      #pragma unroll
      for (int r = 0; r < 4; ++r) {
        rs[0][r] = __shfl(scl2[0], 4 * g16 + r, 64);
        rs[1][r] = __shfl(scl2[1], 4 * g16 + r, 64);
      }
      #pragma unroll
      for (int qi = 0; qi < 2; ++qi)
        #pragma unroll
        for (int cf = 0; cf < 8; ++cf)
          #pragma unroll
          for (int r = 0; r < 4; ++r)
            yacc[qi][cf][r] *= rs[qi][r];
    }

    // ---- PV: y[q][c] += P[q][m] * g[m][c] ----
    #pragma unroll
    for (int ms = 0; ms < 2; ++ms) {
      const int mb = ms * 64 + g16 * 16;
      const int q0w = l15, q1w = l15 + 16;
      f16x8 pa0 = *(const f16x8*)(PlB + (wid << 12) + q0w * 128 + (mb ^ ((q0w & 7) << 4)));
      f16x8 pa1 = *(const f16x8*)(PlB + (wid << 12) + q1w * 128 + (mb ^ ((q1w & 7) << 4)));
      #pragma unroll
      for (int cf = 0; cf < 8; ++cf) {
        const int c = 16 * cf + l15;
        f16x8 gb = *(const f16x8*)(GlB + c * 128 + (mb ^ ((c & 7) << 4)));
        yacc[0][cf] = __builtin_amdgcn_mfma_f32_16x16x32_f16(pa0, gb, yacc[0][cf], 0, 0, 0);
        yacc[1][cf] = __builtin_amdgcn_mfma_f32_16x16x32_f16(pa1, gb, yacc[1][cf], 0, 0, 0);
      }
    }

    __syncthreads();
    if (pf) {
      #pragma unroll
      for (int i = 0; i < 4; ++i) {
        int idx = i * 256 + tid, m = idx >> 4, cg = idx & 15;
        *(int4*)(PhB + m * 256 + ((cg * 16) ^ ((m & 7) << 4))) = stA[i];
      }
      #pragma unroll
      for (int i = 0; i < 4; ++i) {
        int idx = i * 256 + tid, c = idx >> 3, cg = idx & 7;
        *(int4*)(GlB + c * 128 + ((cg * 16) ^ ((c & 7) << 4))) = stB[i];
      }
    }
    __syncthreads();
  }

  // ---- epilogue: divide by l, store y fp32 [c][n] ----
  float iv[2][4];
  #pragma unroll
  for (int r = 0; r < 4; ++r) {
    iv[0][r] = 1.0f / __shfl(lrun[0], 4 * g16 + r, 64);
    iv[1][r] = 1.0f / __shfl(lrun[1], 4 * g16 + r, 64);
  }
  #pragma unroll
  for (int qi = 0; qi < 2; ++qi)
    #pragma unroll
    for (int cf = 0; cf < 8; ++cf) {
      f32x4 o;
      #pragma unroll
      for (int r = 0; r < 4; ++r) o[r] = yacc[qi][cf][r] * iv[qi][r];
      *(f32x4*)&ybuf[(size_t)(b * CI + 16 * cf + l15) * NPIX + n0 + wq0 + 16 * qi + 4 * g16] = o;
    }
}

// ---------------- K4: W-conv GEMM: z[b][o][n] -> tpg[b][128+o][n] ----------
__global__ __launch_bounds__(256) void k_wconv(
    const float* __restrict__ ybuf,
    const float* __restrict__ Ww, const float* __restrict__ bw,
    float* __restrict__ tpg)
{
  const int pt = blockIdx.x, ot = blockIdx.y, b = blockIdx.z;
  const int p0 = pt * 64, o0 = ot * 64;
  __shared__ float Wl[64][33];
  __shared__ float Xl[32][68];
  const int t = threadIdx.x;
  const int to = t >> 4, tp = t & 15;
  float acc[4][4] = {{0.f}};
  for (int kk = 0; kk < CI; kk += 32) {
    #pragma unroll
    for (int i = 0; i < 8; ++i) {
      int idx = i * 256 + t, r = idx >> 5, c = idx & 31;
      Wl[r][c] = Ww[(o0 + r) * CI + kk + c];
    }
    #pragma unroll
    for (int i = 0; i < 8; ++i) {
      int idx = i * 256 + t, r = idx >> 6, c = idx & 63;
      Xl[r][c] = ybuf[(size_t)(b * CI + kk + r) * NPIX + p0 + c];
    }
    __syncthreads();
    #pragma unroll 8
    for (int k = 0; k < 32; ++k) {
      float a[4];
      #pragma unroll
      for (int i = 0; i < 4; ++i) a[i] = Wl[to * 4 + i][k];
      float4 bv = *(const float4*)&Xl[k][tp * 4];
      float bb[4] = {bv.x, bv.y, bv.z, bv.w};
      #pragma unroll
      for (int i = 0; i < 4; ++i)
        #pragma unroll
        for (int j = 0; j < 4; ++j)
          acc[i][j] += a[i] * bb[j];
    }
    __syncthreads();
  }
  #pragma unroll
  for (int i = 0; i < 4; ++i) {
    int o = o0 + to * 4 + i;
    float bias = bw[o];
    float4 v = make_float4(acc[i][0] + bias, acc[i][1] + bias,
                           acc[i][2] + bias, acc[i][3] + bias);
    *(float4*)&tpg[(size_t)(b * 384 + 128 + o) * NPIX + p0 + tp * 4] = v;
  }
}

// ---------------- K4b: per-channel batch stats -----------------------------
__global__ __launch_bounds__(256) void k_stats(
    const float* __restrict__ tpg, float* __restrict__ stats)
{
  const int o = blockIdx.x, t = threadIdx.x;
  float s = 0.f, s2 = 0.f;
  for (int b = 0; b < BB; ++b) {
    const float* z = &tpg[(size_t)(b * 384 + 128 + o) * NPIX];
    for (int i = t; i < NPIX / 4; i += 256) {
      float4 v = *(const float4*)&z[i * 4];
      s  += v.x + v.y + v.z + v.w;
      s2 += v.x * v.x + v.y * v.y + v.z * v.z + v.w * v.w;
    }
  }
  #pragma unroll
  for (int off = 1; off < 64; off <<= 1) {
    s  += __shfl_xor(s,  off, 64);
    s2 += __shfl_xor(s2, off, 64);
  }
  __shared__ float ls[4], ls2[4];
  if ((t & 63) == 0) { ls[t >> 6] = s; ls2[t >> 6] = s2; }
  __syncthreads();
  if (t == 0) {
    float S  = ls[0] + ls[1] + ls[2] + ls[3];
    float S2 = ls2[0] + ls2[1] + ls2[2] + ls2[3];
    const float invn = 1.0f / (float)(BB * NPIX);
    float mean = S * invn;
    float var  = S2 * invn - mean * mean;
    stats[o] = mean;
    stats[CC + o] = rsqrtf(var + 1e-5f);
  }
}

// ---------------- K5: BN apply + residual ----------------------------------
__global__ __launch_bounds__(256) void k_out(
    const float* __restrict__ tpg, const float* __restrict__ x,
    const float* __restrict__ gamma, const float* __restrict__ beta,
    const float* __restrict__ stats, float* __restrict__ out)
{
  int idx = blockIdx.x * 256 + threadIdx.x;
  const int total4 = BB * CC * NPIX / 4;
  if (idx >= total4) return;
  size_t e = (size_t)idx * 4;
  int p = (int)(e % NPIX);
  int o = (int)((e / NPIX) % CC);
  int b = (int)(e / ((size_t)CC * NPIX));
  float a  = stats[CC + o] * gamma[o];
  float c0 = beta[o] - stats[o] * a;
  float4 z  = *(const float4*)&tpg[(size_t)(b * 384 + 128 + o) * NPIX + p];
  float4 xv = *(const float4*)&x[e];
  float4 rv;
  rv.x = z.x * a + c0 + xv.x;
  rv.y = z.y * a + c0 + xv.y;
  rv.z = z.z * a + c0 + xv.z;
  rv.w = z.w * a + c0 + xv.w;
  *(float4*)&out[e] = rv;
}

extern "C" void kernel_launch(void* const* d_in, const int* in_sizes, int n_in,
                              void* d_out, int out_size, void* d_ws, size_t ws_size,
                              hipStream_t stream)
{
  const float* x     = (const float*)d_in[0];
  const float* Wg    = (const float*)d_in[1];
  const float* bg    = (const float*)d_in[2];
  const float* Wt    = (const float*)d_in[3];
  const float* bt    = (const float*)d_in[4];
  const float* Wp    = (const float*)d_in[5];
  const float* bp    = (const float*)d_in[6];
  const float* Ww    = (const float*)d_in[7];
  const float* bw    = (const float*)d_in[8];
  const float* gamma = (const float*)d_in[9];
  const float* beta  = (const float*)d_in[10];
  float* out = (float*)d_out;

  float* ws    = (float*)d_ws;
  float* tpg   = ws;                                   // [4][384][9216] f32
  float* ybuf  = tpg + (size_t)BB * 384 * NPIX;        // [4][128][9216] f32
  float* stats = ybuf + (size_t)BB * CI * NPIX;        // [2][256] f32
  _Float16* th_h  = (_Float16*)(stats + 512);          // [4][9216][128] f16
  _Float16* phi_h = th_h + (size_t)BB * NPIX * CI;     // [4][2304][128] f16
  _Float16* g_h   = phi_h + (size_t)BB * MPIX * CI;    // [4][128][2304] f16

  dim3 g1(NPIX / 64, 384 / 64, BB);
  k_conv3<<<g1, 256, 0, stream>>>(x, Wt, bt, Wg, bg, Wp, bp, tpg);

  dim3 g2a(NPIX / 64, 2, BB);
  k_mkq<<<g2a, 256, 0, stream>>>(tpg, th_h);

  dim3 g2b(MPIX / 64, 4, BB);
  k_pool2<<<g2b, 256, 0, stream>>>(tpg, g_h, phi_h);

  dim3 g3(NPIX / 128, BB);
  k_attn<<<g3, 256, 0, stream>>>(th_h, phi_h, g_h, ybuf);

  dim3 g4(NPIX / 64, CC / 64, BB);
  k_wconv<<<g4, 256, 0, stream>>>(ybuf, Ww, bw, tpg);

  k_stats<<<CC, 256, 0, stream>>>(tpg, stats);

  k_out<<<(BB * CC * NPIX / 4 + 255) / 256, 256, 0, stream>>>(tpg, x, gamma, beta, stats, out);
}

// Round 5
// 236.272 us; speedup vs baseline: 4.8219x; 1.6861x over previous
//
#include <hip/hip_runtime.h>
#include <hip/hip_bf16.h>

#define BB 4
#define CC 256
#define CI 128
#define NPIX 9216      // 96*96
#define MPIX 2304      // 48*48
#define WIMG 96
#define WPOOL 48

typedef _Float16 f16x2 __attribute__((ext_vector_type(2)));
typedef _Float16 f16x4 __attribute__((ext_vector_type(4)));
typedef _Float16 f16x8 __attribute__((ext_vector_type(8)));
typedef float f32x4 __attribute__((ext_vector_type(4)));

// ---------------- K0: weights fp32 -> fp16 ---------------------------------
__global__ __launch_bounds__(256) void k_prep(
    const float* __restrict__ Wt, const float* __restrict__ Wg,
    const float* __restrict__ Wp, const float* __restrict__ Ww,
    _Float16* __restrict__ Wall, _Float16* __restrict__ Wwh)
{
  int i = blockIdx.x * 256 + threadIdx.x;
  if (i < 98304) {
    int o = i >> 8, c = i & 255;
    float v = (o < 128) ? Wt[o * 256 + c]
            : (o < 256) ? Wg[(o - 128) * 256 + c]
                        : Wp[(o - 256) * 256 + c];
    Wall[i] = (_Float16)v;
  } else {
    int j = i - 98304;
    Wwh[j] = (_Float16)Ww[j];
  }
}

// ---------------- K0b: x transpose -> xt[b][p][c] fp16 ---------------------
__global__ __launch_bounds__(256) void k_xt(
    const float* __restrict__ x, _Float16* __restrict__ xt)
{
  const int nt = blockIdx.x, ct = blockIdx.y, b = blockIdx.z;
  const int n0 = nt * 64, c0 = ct * 64;
  __shared__ float L[64][65];
  const int t = threadIdx.x;
  #pragma unroll
  for (int i = 0; i < 16; ++i) {
    int idx = i * 256 + t, c = idx >> 6, n = idx & 63;
    L[c][n] = x[(size_t)(b * CC + c0 + c) * NPIX + n0 + n];
  }
  __syncthreads();
  #pragma unroll
  for (int i = 0; i < 4; ++i) {
    int idx = i * 256 + t, n = idx >> 4, cg = idx & 15;
    f16x4 v;
    v[0] = (_Float16)L[cg * 4 + 0][n]; v[1] = (_Float16)L[cg * 4 + 1][n];
    v[2] = (_Float16)L[cg * 4 + 2][n]; v[3] = (_Float16)L[cg * 4 + 3][n];
    *(f16x4*)&xt[(size_t)(b * NPIX + n0 + n) * 256 + c0 + cg * 4] = v;
  }
}

// ---------------- K1: theta/g/phi convs, fp16 MFMA -------------------------
// D[o][p] = Wall[o][k] xt[p][k]^T. ot=0: theta -> transpose epilogue th_h[n][c].
// ot=1,2: g/phi -> gphi[b][ch][p] full-res fp16.
__global__ __launch_bounds__(256) void k_convA(
    const _Float16* __restrict__ xt, const _Float16* __restrict__ Wall,
    const float* __restrict__ bt, const float* __restrict__ bg,
    const float* __restrict__ bp,
    _Float16* __restrict__ th_h, _Float16* __restrict__ gphi)
{
  const int pt = blockIdx.x, ot = blockIdx.y, b = blockIdx.z;
  const int p0 = pt * 128, o0 = ot * 128;
  __shared__ char smem[34816];   // stage: Ws@0 8KB, Xs@8192 8KB; theta-T reuses all
  char* WsB = smem;
  char* XsB = smem + 8192;
  const int tid = threadIdx.x;
  const int l = tid & 63, w = tid >> 6;
  const int l15 = l & 15, g16 = l >> 4;
  const int wo = (w & 1) * 64, wp = (w >> 1) * 64;

  f32x4 acc[4][4] = {};
  for (int k0 = 0; k0 < 256; k0 += 32) {
    #pragma unroll
    for (int i = 0; i < 2; ++i) {
      int idx = i * 256 + tid, r = idx >> 2, cg = idx & 3;
      int sw = (cg ^ ((r >> 1) & 3)) * 16;
      *(int4*)(WsB + r * 64 + sw) =
          *(const int4*)&Wall[(size_t)(o0 + r) * 256 + k0 + cg * 8];
      *(int4*)(XsB + r * 64 + sw) =
          *(const int4*)&xt[(size_t)(b * NPIX + p0 + r) * 256 + k0 + cg * 8];
    }
    __syncthreads();
    f16x8 af[4], bf[4];
    #pragma unroll
    for (int f = 0; f < 4; ++f) {
      int ro = wo + f * 16 + l15;
      af[f] = *(const f16x8*)(WsB + ro * 64 + ((g16 ^ ((ro >> 1) & 3)) * 16));
      int rp = wp + f * 16 + l15;
      bf[f] = *(const f16x8*)(XsB + rp * 64 + ((g16 ^ ((rp >> 1) & 3)) * 16));
    }
    #pragma unroll
    for (int of = 0; of < 4; ++of)
      #pragma unroll
      for (int pf = 0; pf < 4; ++pf)
        acc[of][pf] = __builtin_amdgcn_mfma_f32_16x16x32_f16(af[of], bf[pf], acc[of][pf], 0, 0, 0);
    __syncthreads();
  }

  if (o0 == 0) {
    // theta: bias, fp16, transpose via LDS -> th_h[b][n][c]
    _Float16* T = (_Float16*)smem;   // [128][136]
    #pragma unroll
    for (int of = 0; of < 4; ++of) {
      const float4 bb = *(const float4*)&bt[wo + of * 16 + g16 * 4];
      float bv[4] = {bb.x, bb.y, bb.z, bb.w};
      #pragma unroll
      for (int pf = 0; pf < 4; ++pf) {
        f16x4 v;
        #pragma unroll
        for (int r = 0; r < 4; ++r) v[r] = (_Float16)(acc[of][pf][r] + bv[r]);
        *(f16x4*)&T[(wp + pf * 16 + l15) * 136 + wo + of * 16 + g16 * 4] = v;
      }
    }
    __syncthreads();
    #pragma unroll
    for (int i = 0; i < 8; ++i) {
      int idx = i * 256 + tid, row = idx >> 4, cg = idx & 15;
      *(int4*)&th_h[(size_t)(b * NPIX + p0 + row) * 128 + cg * 8] =
          *(const int4*)&T[row * 136 + cg * 8];
    }
  } else {
    const float* bsel = (o0 == 128) ? bg : bp;
    const int chbase = o0 - 128;   // g -> 0..127, phi -> 128..255
    #pragma unroll
    for (int of = 0; of < 4; ++of) {
      const float4 bb = *(const float4*)&bsel[wo + of * 16 + g16 * 4];
      float bv[4] = {bb.x, bb.y, bb.z, bb.w};
      #pragma unroll
      for (int pf = 0; pf < 4; ++pf)
        #pragma unroll
        for (int r = 0; r < 4; ++r) {
          int ch = chbase + wo + of * 16 + g16 * 4 + r;
          gphi[(size_t)(b * 256 + ch) * NPIX + p0 + wp + pf * 16 + l15] =
              (_Float16)(acc[of][pf][r] + bv[r]);
        }
    }
  }
}

// ---------------- K2: 2x2 maxpool fp16 -> g_h[c][m], phi_h[m][c] -----------
__global__ __launch_bounds__(256) void k_pool2(
    const _Float16* __restrict__ gphi,
    _Float16* __restrict__ g_h, _Float16* __restrict__ phi_h)
{
  const int mt = blockIdx.x, ct = blockIdx.y, b = blockIdx.z;
  const int m0 = mt * 64, c0 = ct * 32;
  __shared__ _Float16 Lg[32][72], Lp[32][72];
  const int t = threadIdx.x;
  #pragma unroll
  for (int i = 0; i < 8; ++i) {
    int idx = i * 256 + t, c = idx >> 6, m = idx & 63;
    int mm = m0 + m, hp = mm / WPOOL, wp = mm % WPOOL;
    const _Float16* sg = &gphi[(size_t)(b * 256 + c0 + c) * NPIX + hp * 192 + wp * 2];
    f16x2 a0 = *(const f16x2*)sg;
    f16x2 a1 = *(const f16x2*)(sg + WIMG);
    Lg[c][m] = (_Float16)fmaxf(fmaxf((float)a0[0], (float)a0[1]),
                               fmaxf((float)a1[0], (float)a1[1]));
    const _Float16* sp = sg + (size_t)128 * NPIX;
    f16x2 b0 = *(const f16x2*)sp;
    f16x2 b1 = *(const f16x2*)(sp + WIMG);
    Lp[c][m] = (_Float16)fmaxf(fmaxf((float)b0[0], (float)b0[1]),
                               fmaxf((float)b1[0], (float)b1[1]));
  }
  __syncthreads();
  {
    int c = t >> 3, mq = t & 7;
    f16x8 v = *(const f16x8*)&Lg[c][mq * 8];
    *(f16x8*)&g_h[(size_t)(b * CI + c0 + c) * MPIX + m0 + mq * 8] = v;
  }
  #pragma unroll
  for (int i = 0; i < 2; ++i) {
    int idx = i * 256 + t, m = idx >> 3, cg = idx & 7;
    f16x4 v;
    v[0] = Lp[cg * 4 + 0][m]; v[1] = Lp[cg * 4 + 1][m];
    v[2] = Lp[cg * 4 + 2][m]; v[3] = Lp[cg * 4 + 3][m];
    *(f16x4*)&phi_h[(size_t)(b * MPIX + m0 + m) * 128 + c0 + cg * 4] = v;
  }
}

// ---------------- K3: flash attention, fp16 MFMA ----------------------------
// Q-tile 128 (4 waves x 32 q). K-tile 64. Swapped QK^T: S^T = mfma(phi, theta)
// so softmax rows are lane-local. Epilogue: LDS transpose -> y_h[b][n][c] fp16.
__global__ __launch_bounds__(256, 2) void k_attn(
    const _Float16* __restrict__ th_h,
    const _Float16* __restrict__ phi_h,
    const _Float16* __restrict__ g_h,
    _Float16* __restrict__ y_h)
{
  const int qt = blockIdx.x, b = blockIdx.y;
  const int n0 = qt * 128;
  __shared__ char smem[49152];
  char* PhB = smem;            // phi tile [m][c] swizzled, 16 KB
  char* GlB = smem + 16384;    // g tile [c][m] swizzled, 16 KB
  char* PlB = smem + 32768;    // per-wave P, swizzled, 16 KB

  const int tid = threadIdx.x;
  const int l = tid & 63, wid = tid >> 6;
  const int l15 = l & 15, g16 = l >> 4;
  const int wq0 = wid * 32;

  f16x8 thf[2][4];
  #pragma unroll
  for (int qh = 0; qh < 2; ++qh) {
    const size_t row = (size_t)(b * NPIX + n0 + wq0 + 16 * qh + l15) * 128;
    #pragma unroll
    for (int cs = 0; cs < 4; ++cs)
      thf[qh][cs] = *(const f16x8*)&th_h[row + 32 * cs + 8 * g16];
  }

  #pragma unroll
  for (int i = 0; i < 4; ++i) {
    int idx = i * 256 + tid, m = idx >> 4, cg = idx & 15;
    int4 v = *(const int4*)&phi_h[((size_t)(b * MPIX + m) << 7) + cg * 8];
    *(int4*)(PhB + m * 256 + ((cg * 16) ^ ((m & 7) << 4))) = v;
  }
  #pragma unroll
  for (int i = 0; i < 4; ++i) {
    int idx = i * 256 + tid, c = idx >> 3, cg = idx & 7;
    int4 v = *(const int4*)&g_h[(size_t)(b * CI + c) * MPIX + cg * 8];
    *(int4*)(GlB + c * 128 + ((cg * 16) ^ ((c & 7) << 4))) = v;
  }
  __syncthreads();

  f32x4 yacc[2][8] = {};
  float mrun[2] = {-1e30f, -1e30f};
  float lrun[2] = {0.f, 0.f};

  for (int kt = 0; kt < 36; ++kt) {
    int4 stA[4], stB[4];
    const bool pf = (kt + 1 < 36);
    if (pf) {
      const int m1 = (kt + 1) * 64;
      #pragma unroll
      for (int i = 0; i < 4; ++i) {
        int idx = i * 256 + tid, m = idx >> 4, cg = idx & 15;
        stA[i] = *(const int4*)&phi_h[((size_t)(b * MPIX + m1 + m) << 7) + cg * 8];
      }
      #pragma unroll
      for (int i = 0; i < 4; ++i) {
        int idx = i * 256 + tid, c = idx >> 3, cg = idx & 7;
        stB[i] = *(const int4*)&g_h[(size_t)(b * CI + c) * MPIX + m1 + cg * 8];
      }
    }

    // ---- scores: S^T[m][q] ----
    f32x4 sacc[4][2] = {};
    #pragma unroll
    for (int cs = 0; cs < 4; ++cs) {
      const int cb = cs * 64 + g16 * 16;
      #pragma unroll
      for (int mf = 0; mf < 4; ++mf) {
        const int m = 16 * mf + l15;
        f16x8 aph = *(const f16x8*)(PhB + m * 256 + (cb ^ ((m & 7) << 4)));
        sacc[mf][0] = __builtin_amdgcn_mfma_f32_16x16x32_f16(aph, thf[0][cs], sacc[mf][0], 0, 0, 0);
        sacc[mf][1] = __builtin_amdgcn_mfma_f32_16x16x32_f16(aph, thf[1][cs], sacc[mf][1], 0, 0, 0);
      }
    }

    // ---- online softmax (lane owns q = wq0 + 16*qh + l15) ----
    float scl2[2];
    f16x4 pr[4][2];
    #pragma unroll
    for (int qh = 0; qh < 2; ++qh) {
      float mx = -1e30f;
      #pragma unroll
      for (int mf = 0; mf < 4; ++mf)
        #pragma unroll
        for (int r = 0; r < 4; ++r) mx = fmaxf(mx, sacc[mf][qh][r]);
      mx = fmaxf(mx, __shfl_xor(mx, 16, 64));
      mx = fmaxf(mx, __shfl_xor(mx, 32, 64));
      const float mo = mrun[qh];
      const float mn = fmaxf(mo, mx);
      float sum = 0.f;
      #pragma unroll
      for (int mf = 0; mf < 4; ++mf)
        #pragma unroll
        for (int r = 0; r < 4; ++r) {
          float p = __expf(sacc[mf][qh][r] - mn);
          _Float16 ph = (_Float16)p;
          pr[mf][qh][r] = ph;
          sum += (float)ph;
        }
      sum += __shfl_xor(sum, 16, 64);
      sum += __shfl_xor(sum, 32, 64);
      const float sc = __expf(mo - mn);
      scl2[qh] = sc;
      lrun[qh] = lrun[qh] * sc + sum;
      mrun[qh] = mn;
    }

    // ---- P -> wave-private LDS (fp16, swizzled) ----
    #pragma unroll
    for (int qh = 0; qh < 2; ++qh) {
      const int qw = l15 + 16 * qh;
      char* prow = PlB + (wid << 12) + qw * 128;
      #pragma unroll
      for (int mf = 0; mf < 4; ++mf)
        *(f16x4*)(prow + ((32 * mf + 8 * g16) ^ ((qw & 7) << 4))) = pr[mf][qh];
    }

    // ---- rescale yacc ----
    {
      float rs[2][4];
      #pragma unroll
      for (int r = 0; r < 4; ++r) {
        rs[0][r] = __shfl(scl2[0], 4 * g16 + r, 64);
        rs[1][r] = __shfl(scl2[1], 4 * g16 + r, 64);
      }
      #pragma unroll
      for (int qi = 0; qi < 2; ++qi)
        #pragma unroll
        for (int cf = 0; cf < 8; ++cf)
          #pragma unroll
          for (int r = 0; r < 4; ++r)
            yacc[qi][cf][r] *= rs[qi][r];
    }

    // ---- PV ----
    #pragma unroll
    for (int ms = 0; ms < 2; ++ms) {
      const int mb = ms * 64 + g16 * 16;
      const int q0w = l15, q1w = l15 + 16;
      f16x8 pa0 = *(const f16x8*)(PlB + (wid << 12) + q0w * 128 + (mb ^ ((q0w & 7) << 4)));
      f16x8 pa1 = *(const f16x8*)(PlB + (wid << 12) + q1w * 128 + (mb ^ ((q1w & 7) << 4)));
      #pragma unroll
      for (int cf = 0; cf < 8; ++cf) {
        const int c = 16 * cf + l15;
        f16x8 gb = *(const f16x8*)(GlB + c * 128 + (mb ^ ((c & 7) << 4)));
        yacc[0][cf] = __builtin_amdgcn_mfma_f32_16x16x32_f16(pa0, gb, yacc[0][cf], 0, 0, 0);
        yacc[1][cf] = __builtin_amdgcn_mfma_f32_16x16x32_f16(pa1, gb, yacc[1][cf], 0, 0, 0);
      }
    }

    __syncthreads();
    if (pf) {
      #pragma unroll
      for (int i = 0; i < 4; ++i) {
        int idx = i * 256 + tid, m = idx >> 4, cg = idx & 15;
        *(int4*)(PhB + m * 256 + ((cg * 16) ^ ((m & 7) << 4))) = stA[i];
      }
      #pragma unroll
      for (int i = 0; i < 4; ++i) {
        int idx = i * 256 + tid, c = idx >> 3, cg = idx & 7;
        *(int4*)(GlB + c * 128 + ((cg * 16) ^ ((c & 7) << 4))) = stB[i];
      }
    }
    __syncthreads();
  }

  // ---- epilogue: divide by l, LDS transpose, store y_h[b][n][c] fp16 ----
  float iv[2][4];
  #pragma unroll
  for (int r = 0; r < 4; ++r) {
    iv[0][r] = 1.0f / __shfl(lrun[0], 4 * g16 + r, 64);
    iv[1][r] = 1.0f / __shfl(lrun[1], 4 * g16 + r, 64);
  }
  _Float16* Yl = (_Float16*)smem;   // [128][136]
  #pragma unroll
  for (int qi = 0; qi < 2; ++qi)
    #pragma unroll
    for (int cf = 0; cf < 8; ++cf)
      #pragma unroll
      for (int r = 0; r < 4; ++r)
        Yl[(wq0 + 16 * qi + 4 * g16 + r) * 136 + 16 * cf + l15] =
            (_Float16)(yacc[qi][cf][r] * iv[qi][r]);
  __syncthreads();
  #pragma unroll
  for (int i = 0; i < 8; ++i) {
    int idx = i * 256 + tid, row = idx >> 4, cg = idx & 15;
    *(int4*)&y_h[(size_t)(b * NPIX + n0 + row) * 128 + cg * 8] =
        *(const int4*)&Yl[row * 136 + cg * 8];
  }
}

// ---------------- K4: W-conv fp16 MFMA: z[b][o][n] fp32 --------------------
__global__ __launch_bounds__(256) void k_wconv(
    const _Float16* __restrict__ y_h, const _Float16* __restrict__ Wwh,
    const float* __restrict__ bw, float* __restrict__ zbuf)
{
  const int nt = blockIdx.x, ot = blockIdx.y, b = blockIdx.z;
  const int n0 = nt * 128, o0 = ot * 128;
  __shared__ char smem[16384];
  char* WsB = smem;
  char* YsB = smem + 8192;
  const int tid = threadIdx.x;
  const int l = tid & 63, w = tid >> 6;
  const int l15 = l & 15, g16 = l >> 4;
  const int wo = (w & 1) * 64, wn = (w >> 1) * 64;

  f32x4 acc[4][4] = {};
  for (int k0 = 0; k0 < 128; k0 += 32) {
    #pragma unroll
    for (int i = 0; i < 2; ++i) {
      int idx = i * 256 + tid, r = idx >> 2, cg = idx & 3;
      int sw = (cg ^ ((r >> 1) & 3)) * 16;
      *(int4*)(WsB + r * 64 + sw) =
          *(const int4*)&Wwh[(size_t)(o0 + r) * 128 + k0 + cg * 8];
      *(int4*)(YsB + r * 64 + sw) =
          *(const int4*)&y_h[(size_t)(b * NPIX + n0 + r) * 128 + k0 + cg * 8];
    }
    __syncthreads();
    f16x8 af[4], bf[4];
    #pragma unroll
    for (int f = 0; f < 4; ++f) {
      int ro = wo + f * 16 + l15;
      af[f] = *(const f16x8*)(WsB + ro * 64 + ((g16 ^ ((ro >> 1) & 3)) * 16));
      int rn = wn + f * 16 + l15;
      bf[f] = *(const f16x8*)(YsB + rn * 64 + ((g16 ^ ((rn >> 1) & 3)) * 16));
    }
    #pragma unroll
    for (int of = 0; of < 4; ++of)
      #pragma unroll
      for (int pf = 0; pf < 4; ++pf)
        acc[of][pf] = __builtin_amdgcn_mfma_f32_16x16x32_f16(af[of], bf[pf], acc[of][pf], 0, 0, 0);
    __syncthreads();
  }
  #pragma unroll
  for (int of = 0; of < 4; ++of) {
    const float4 bb = *(const float4*)&bw[o0 + wo + of * 16 + g16 * 4];
    float bv[4] = {bb.x, bb.y, bb.z, bb.w};
    #pragma unroll
    for (int pf = 0; pf < 4; ++pf)
      #pragma unroll
      for (int r = 0; r < 4; ++r)
        zbuf[(size_t)(b * CC + o0 + wo + of * 16 + g16 * 4 + r) * NPIX +
             n0 + wn + pf * 16 + l15] = acc[of][pf][r] + bv[r];
  }
}

// ---------------- K4b: per-channel batch stats -----------------------------
__global__ __launch_bounds__(256) void k_stats(
    const float* __restrict__ zbuf, float* __restrict__ stats)
{
  const int o = blockIdx.x, t = threadIdx.x;
  float s = 0.f, s2 = 0.f;
  for (int b = 0; b < BB; ++b) {
    const float* z = &zbuf[(size_t)(b * CC + o) * NPIX];
    for (int i = t; i < NPIX / 4; i += 256) {
      float4 v = *(const float4*)&z[i * 4];
      s  += v.x + v.y + v.z + v.w;
      s2 += v.x * v.x + v.y * v.y + v.z * v.z + v.w * v.w;
    }
  }
  #pragma unroll
  for (int off = 1; off < 64; off <<= 1) {
    s  += __shfl_xor(s,  off, 64);
    s2 += __shfl_xor(s2, off, 64);
  }
  __shared__ float ls[4], ls2[4];
  if ((t & 63) == 0) { ls[t >> 6] = s; ls2[t >> 6] = s2; }
  __syncthreads();
  if (t == 0) {
    float S  = ls[0] + ls[1] + ls[2] + ls[3];
    float S2 = ls2[0] + ls2[1] + ls2[2] + ls2[3];
    const float invn = 1.0f / (float)(BB * NPIX);
    float mean = S * invn;
    float var  = S2 * invn - mean * mean;
    stats[o] = mean;
    stats[CC + o] = rsqrtf(var + 1e-5f);
  }
}

// ---------------- K5: BN apply + residual ----------------------------------
__global__ __launch_bounds__(256) void k_out(
    const float* __restrict__ zbuf, const float* __restrict__ x,
    const float* __restrict__ gamma, const float* __restrict__ beta,
    const float* __restrict__ stats, float* __restrict__ out)
{
  int idx = blockIdx.x * 256 + threadIdx.x;
  const int total4 = BB * CC * NPIX / 4;
  if (idx >= total4) return;
  size_t e = (size_t)idx * 4;
  int p = (int)(e % NPIX);
  int o = (int)((e / NPIX) % CC);
  int b = (int)(e / ((size_t)CC * NPIX));
  float a  = stats[CC + o] * gamma[o];
  float c0 = beta[o] - stats[o] * a;
  float4 z  = *(const float4*)&zbuf[(size_t)(b * CC + o) * NPIX + p];
  float4 xv = *(const float4*)&x[e];
  float4 rv;
  rv.x = z.x * a + c0 + xv.x;
  rv.y = z.y * a + c0 + xv.y;
  rv.z = z.z * a + c0 + xv.z;
  rv.w = z.w * a + c0 + xv.w;
  *(float4*)&out[e] = rv;
}

extern "C" void kernel_launch(void* const* d_in, const int* in_sizes, int n_in,
                              void* d_out, int out_size, void* d_ws, size_t ws_size,
                              hipStream_t stream)
{
  const float* x     = (const float*)d_in[0];
  const float* Wg    = (const float*)d_in[1];
  const float* bg    = (const float*)d_in[2];
  const float* Wt    = (const float*)d_in[3];
  const float* bt    = (const float*)d_in[4];
  const float* Wp    = (const float*)d_in[5];
  const float* bp    = (const float*)d_in[6];
  const float* Ww    = (const float*)d_in[7];
  const float* bw    = (const float*)d_in[8];
  const float* gamma = (const float*)d_in[9];
  const float* beta  = (const float*)d_in[10];
  float* out = (float*)d_out;

  // workspace layout (lifetime-aliased):
  //  region A (37,748,736 B): xt fp16 [4][9216][256] (first 18.9 MB), later zbuf f32 [4][256][9216]
  //  region B (18,874,368 B): gphi fp16 [4][256][9216], later y_h fp16 [4][9216][128]
  char* wsb = (char*)d_ws;
  float*    zbuf  = (float*)wsb;
  _Float16* xt    = (_Float16*)wsb;
  char* p2 = wsb + 37748736;
  _Float16* gphi  = (_Float16*)p2;
  _Float16* y_h   = (_Float16*)p2;
  char* p3 = p2 + 18874368;
  _Float16* th_h  = (_Float16*)p3;                      //  9,437,184
  _Float16* g_h   = (_Float16*)(p3 + 9437184);          //  2,359,296
  _Float16* phi_h = (_Float16*)(p3 + 11796480);         //  2,359,296
  _Float16* Wall  = (_Float16*)(p3 + 14155776);         //    196,608
  _Float16* Wwh   = (_Float16*)(p3 + 14352384);         //     65,536
  float*    stats = (float*)(p3 + 14417920);            //      2,048

  k_prep<<<512, 256, 0, stream>>>(Wt, Wg, Wp, Ww, Wall, Wwh);

  dim3 gxt(NPIX / 64, CC / 64, BB);
  k_xt<<<gxt, 256, 0, stream>>>(x, xt);

  dim3 g1(NPIX / 128, 3, BB);
  k_convA<<<g1, 256, 0, stream>>>(xt, Wall, bt, bg, bp, th_h, gphi);

  dim3 g2(MPIX / 64, 4, BB);
  k_pool2<<<g2, 256, 0, stream>>>(gphi, g_h, phi_h);

  dim3 g3(NPIX / 128, BB);
  k_attn<<<g3, 256, 0, stream>>>(th_h, phi_h, g_h, y_h);

  dim3 g4(NPIX / 128, CC / 128, BB);
  k_wconv<<<g4, 256, 0, stream>>>(y_h, Wwh, bw, zbuf);

  k_stats<<<CC, 256, 0, stream>>>(zbuf, stats);

  k_out<<<(BB * CC * NPIX / 4 + 255) / 256, 256, 0, stream>>>(zbuf, x, gamma, beta, stats, out);
}